// Round 1
// 209.565 us; speedup vs baseline: 1.3176x; 1.3176x over previous
//
#include <hip/hip_runtime.h>
#include <math.h>

// ================= SSMInterBlock v10: split-bf16 MFMA for P-A / P-D =========
// R0 theory: v9 counters = VALUBusy 55.7%, MfmaUtil 0, HBM 2.8%, 0 bank-conf.
// -> VALU-instruction bound; 2/3 of VALU are two dense per-block GEMMs:
//    P-A [32x96]@[96x384], P-D [32x192]@[192x96]  (M = 8 seqs x 4 l).
// Move both onto v_mfma_f32_16x16x32_bf16 with 2-term bf16 compensation
// (D = AhBh + AlBh + AhBl, fp32 accum; rel err ~2^-15 -> absmax unchanged).
// Weights pre-split + pre-swizzled into B-fragment order by prep_weights
// (ws stays 238 KB). Block-cooperative: stage x -> MFMA P-A -> silu/scatter
// u,z -> per-wave P-B/scan/LN (proven v9 code, u/z via LDS) -> MFMA P-D ->
// coalesced store. Predicted: dur 276 -> ~160us, MfmaUtil 0 -> ~4%,
// VALUBusy -> ~45%, LDS 29.7 -> 61.7 KB (2 blocks/CU).

#define THREADS 256
#define SEQ_PB  8
#define DM      96
#define DE      192
#define NJ      384
#define NST     16
#define RNK     6
#define NC      38

typedef short short8 __attribute__((ext_vector_type(8)));
typedef float f32x4  __attribute__((ext_vector_type(4)));

// ---- ws layout: ushort indices (bf16 fragment tables)
#define UO_B1H 0        // [3 kt][24 nt][64 lane][8] : bf16-hi of W1^T  B-frags
#define UO_B1L 36864
#define UO_WOH 73728    // [6 kt][6 nt][64 lane][8]  : bf16-hi of Wout^T B-frags
#define UO_WOL 92160    // ushort end 110592 == byte 221184
// ---- ws layout: float indices
#define FO_NAT 55296    // [16][192]  nat[n][d] = -exp(A_logs[d][n])
#define FO_DTT 58368    // [6][192]   dtt[r][d] = w_dt[d][r]   (end 238,080 B)

// ---- LDS layout (floats)
#define XSTR   388      // x-stage per-seq stride (388%32=4 -> bank spread)
#define XDSTR  152      // x_dbl per-seq stride (overlays A-region after P-A)
#define UZSTR  1540     // u(768) + z(768) + pad4 per seq (1540%32=4)
#define AS_OFF 0        // A-region: x-stage -> x_dbl -> out-stage (3104 f)
#define UZ_OFF 3104
#define LDS_F  15424    // 61,696 B -> 2 blocks/CU

#define MFMA(A, B, C) __builtin_amdgcn_mfma_f32_16x16x32_bf16(A, B, C, 0, 0, 0)

#define BF16_SPLIT(F, H, L) { \
    unsigned fb_ = __float_as_uint(F); \
    H = (short)(fb_ >> 16); \
    float fh_ = __uint_as_float(fb_ & 0xffff0000u); \
    L = (short)(__float_as_uint((F) - fh_) >> 16); }

__device__ __forceinline__ float softplus_f(float x) {
    return fmaxf(x, 0.f) + log1pf(__expf(-fabsf(x)));
}
__device__ __forceinline__ float silu_f(float x) {
    return x / (1.f + __expf(-x));
}
__device__ __forceinline__ float4 fma4(float w, float4 x, float4 a) {
    a.x = fmaf(w, x.x, a.x); a.y = fmaf(w, x.y, a.y);
    a.z = fmaf(w, x.z, a.z); a.w = fmaf(w, x.w, a.w);
    return a;
}

__global__ void prep_weights(const float* __restrict__ w_in,
                             const float* __restrict__ w_out,
                             const float* __restrict__ a_logs,
                             const float* __restrict__ w_dt,
                             float* __restrict__ ws) {
    unsigned short* wsu = (unsigned short*)ws;
    int t0 = blockIdx.x * blockDim.x + threadIdx.x;
    int stride = gridDim.x * blockDim.x;
    // W1^T bf16 hi/lo B-fragments: B[k=d][n=j], frag lane holds n=lane&15,
    // k = kt*32 + (lane>>4)*8 + e  (e=0..7)
    for (int t = t0; t < 3 * 24 * 512; t += stride) {
        int kt = t / 12288, rem = t % 12288;
        int nt = rem / 512, q = rem % 512;
        int ln = q >> 3, j = q & 7;
        int d = kt * 32 + (ln >> 4) * 8 + j;
        int n = nt * 16 + (ln & 15);
        float f = w_in[n * DM + d];            // W1T[d][n]
        short h, l; BF16_SPLIT(f, h, l)
        wsu[UO_B1H + t] = (unsigned short)h;
        wsu[UO_B1L + t] = (unsigned short)l;
    }
    // Wout^T bf16 hi/lo B-fragments: B[k=de][n=dd]
    for (int t = t0; t < 6 * 6 * 512; t += stride) {
        int kt = t / 3072, rem = t % 3072;
        int nt = rem / 512, q = rem % 512;
        int ln = q >> 3, j = q & 7;
        int k = kt * 32 + (ln >> 4) * 8 + j;
        int n = nt * 16 + (ln & 15);
        float f = w_out[n * DE + k];           // WoT[k][n]
        short h, l; BF16_SPLIT(f, h, l)
        wsu[UO_WOH + t] = (unsigned short)h;
        wsu[UO_WOL + t] = (unsigned short)l;
    }
    for (int t = t0; t < NST * DE; t += stride) {
        int n = t / DE, d = t % DE;
        ws[FO_NAT + t] = -__expf(a_logs[d * NST + n]);
    }
    for (int t = t0; t < RNK * DE; t += stride) {
        int r = t / DE, d = t % DE;
        ws[FO_DTT + t] = w_dt[d * RNK + r];
    }
}

// Build an A-fragment (hi+lo) for row-tile MT, k-tile KT from an LDS region
// laid out as region[s*STRIDE_ + 4*k + l] with row m = 4*s + l = MT*16+(lane&15).
#define BUILD_A(AH, AL, MT, KT, BASE_, STRIDE_) { \
    const int m_ = (MT) * 16 + (lane & 15); \
    const float* xr_ = &lds[(BASE_) + (m_ >> 2) * (STRIDE_) + (m_ & 3)]; \
    const int kb_ = (KT) * 32 + (lane >> 4) * 8; \
    _Pragma("unroll") \
    for (int j_ = 0; j_ < 8; ++j_) { \
        float f_ = xr_[4 * (kb_ + j_)]; \
        short h_, l_; BF16_SPLIT(f_, h_, l_) \
        AH[j_] = h_; AL[j_] = l_; \
    } }

__global__ __launch_bounds__(THREADS, 2)
void ssm_fused10(const float* __restrict__ x,       // [nseq][384] = [seq][d][l]
                 const float* __restrict__ w_xp,    // [38][192]
                 const float* __restrict__ b_dt,    // [192]
                 const float* __restrict__ dvec,    // [192]
                 const float* __restrict__ gamma_,  // [192]
                 const float* __restrict__ beta_,   // [192]
                 const float* __restrict__ ws,
                 float* __restrict__ out)           // [nseq][384] = [seq][dd][l]
{
    __shared__ float lds[LDS_F];
    const int tid  = threadIdx.x;
    const int lane = tid & 63;
    const int wv   = __builtin_amdgcn_readfirstlane(tid >> 6);
    const int blk  = blockIdx.x;
    const unsigned short* wsu = (const unsigned short*)ws;

    // ---------- stage x (8 seqs, 12 KB) into bank-padded LDS ----------
    {
        const float4* xg = (const float4*)(x + (size_t)blk * SEQ_PB * NJ);
        for (int i = tid; i < SEQ_PB * NJ / 4; i += THREADS) {
            int s = i / (NJ / 4), off = i % (NJ / 4);
            *(float4*)&lds[AS_OFF + s * XSTR + 4 * off] = xg[i];
        }
    }
    __syncthreads();

    // ---------- P-A: xz = x @ W1^T via split-bf16 MFMA ----------
    // wave wv owns cols n in [96*wv, 96*wv+96) (wv 0,1 -> u; wv 2,3 -> z)
    {
        f32x4 zz = {0.f, 0.f, 0.f, 0.f};
        f32x4 acc[2][6];
        #pragma unroll
        for (int a = 0; a < 2; ++a)
            #pragma unroll
            for (int b = 0; b < 6; ++b) acc[a][b] = zz;

        const short8* b1h = (const short8*)(wsu + UO_B1H);
        const short8* b1l = (const short8*)(wsu + UO_B1L);
        #pragma unroll
        for (int kt = 0; kt < 3; ++kt) {
            short8 ah0, al0, ah1, al1;
            BUILD_A(ah0, al0, 0, kt, AS_OFF, XSTR)
            BUILD_A(ah1, al1, 1, kt, AS_OFF, XSTR)
            #pragma unroll
            for (int t = 0; t < 6; ++t) {
                int fi = (kt * 24 + 6 * wv + t) * 64 + lane;
                short8 bh = b1h[fi];
                short8 bl = b1l[fi];
                acc[0][t] = MFMA(ah0, bh, acc[0][t]);
                acc[1][t] = MFMA(ah1, bh, acc[1][t]);
                acc[0][t] = MFMA(al0, bh, acc[0][t]);
                acc[1][t] = MFMA(al1, bh, acc[1][t]);
                acc[0][t] = MFMA(ah0, bl, acc[0][t]);
                acc[1][t] = MFMA(ah1, bl, acc[1][t]);
            }
        }
        // silu + scatter into per-seq u/z regions.
        // C/D layout: col = lane&15, row = (lane>>4)*4 + reg   [m89-verified]
        const int g = lane >> 4, c = lane & 15;
        const int isz  = (wv >= 2);
        const int zofs = isz ? (4 * DE) : 0;           // z at +768
        const int cb   = 96 * wv - (isz ? DE : 0);     // col base within u or z
        float* uz = &lds[UZ_OFF];
        #pragma unroll
        for (int mt = 0; mt < 2; ++mt) {
            #pragma unroll
            for (int t = 0; t < 6; ++t) {
                int dcol = cb + 16 * t + c;
                #pragma unroll
                for (int r = 0; r < 4; ++r) {
                    int row = mt * 16 + g * 4 + r;     // m = 4*s + l
                    uz[(row >> 2) * UZSTR + zofs + 4 * dcol + (row & 3)] =
                        silu_f(acc[mt][t][r]);
                }
            }
        }
    }
    __syncthreads();

    // ---------- P-B + scan + LN: per-wave, 2 seqs (proven v9 code) ----------
    float* UA  = &lds[UZ_OFF + (2 * wv) * UZSTR];
    float* UB  = UA + UZSTR;
    float* XDA = &lds[AS_OFF + (2 * wv) * XDSTR];   // overlays dead x-stage
    float* XDB = XDA + XDSTR;

    if (lane < NC) {    // x_dbl[c][l], c = lane
        const float* wc = w_xp + lane * DE;
        float4 cA = make_float4(0.f, 0.f, 0.f, 0.f);
        float4 cB = make_float4(0.f, 0.f, 0.f, 0.f);
        #pragma unroll 4
        for (int dq = 0; dq < DE / 4; ++dq) {
            float4 wq  = *(const float4*)&wc[4 * dq];
            float4 qA0 = *(const float4*)&UA[16 * dq + 0];
            float4 qA1 = *(const float4*)&UA[16 * dq + 4];
            float4 qA2 = *(const float4*)&UA[16 * dq + 8];
            float4 qA3 = *(const float4*)&UA[16 * dq + 12];
            float4 qB0 = *(const float4*)&UB[16 * dq + 0];
            float4 qB1 = *(const float4*)&UB[16 * dq + 4];
            float4 qB2 = *(const float4*)&UB[16 * dq + 8];
            float4 qB3 = *(const float4*)&UB[16 * dq + 12];
            cA = fma4(wq.x, qA0, cA); cA = fma4(wq.y, qA1, cA);
            cA = fma4(wq.z, qA2, cA); cA = fma4(wq.w, qA3, cA);
            cB = fma4(wq.x, qB0, cB); cB = fma4(wq.y, qB1, cB);
            cB = fma4(wq.z, qB2, cB); cB = fma4(wq.w, qB3, cB);
        }
        *(float4*)&XDA[4 * lane] = cA;
        *(float4*)&XDB[4 * lane] = cB;
    }

#define SCAN_K(WU, WXD, K, YOUT) { \
    const int d = lane + 64 * (K); \
    float4 U4 = *(const float4*)&WU[4 * d]; \
    float4 t0 = *(const float4*)&WXD[0]; \
    float4 t1 = *(const float4*)&WXD[4]; \
    float4 t2 = *(const float4*)&WXD[8]; \
    float4 t3 = *(const float4*)&WXD[12]; \
    float4 t4 = *(const float4*)&WXD[16]; \
    float4 t5 = *(const float4*)&WXD[20]; \
    const float* dtt = ws + FO_DTT + d; \
    float r0 = dtt[0], r1 = dtt[192], r2 = dtt[384]; \
    float r3 = dtt[576], r4 = dtt[768], r5 = dtt[960]; \
    float d0 = r0 * t0.x, d1 = r0 * t0.y, d2 = r0 * t0.z, d3 = r0 * t0.w; \
    d0 = fmaf(r1, t1.x, d0); d1 = fmaf(r1, t1.y, d1); \
    d2 = fmaf(r1, t1.z, d2); d3 = fmaf(r1, t1.w, d3); \
    d0 = fmaf(r2, t2.x, d0); d1 = fmaf(r2, t2.y, d1); \
    d2 = fmaf(r2, t2.z, d2); d3 = fmaf(r2, t2.w, d3); \
    d0 = fmaf(r3, t3.x, d0); d1 = fmaf(r3, t3.y, d1); \
    d2 = fmaf(r3, t3.z, d2); d3 = fmaf(r3, t3.w, d3); \
    d0 = fmaf(r4, t4.x, d0); d1 = fmaf(r4, t4.y, d1); \
    d2 = fmaf(r4, t4.z, d2); d3 = fmaf(r4, t4.w, d3); \
    d0 = fmaf(r5, t5.x, d0); d1 = fmaf(r5, t5.y, d1); \
    d2 = fmaf(r5, t5.z, d2); d3 = fmaf(r5, t5.w, d3); \
    float bias = b_dt[d]; \
    float dl0 = softplus_f(d0 + bias), dl1 = softplus_f(d1 + bias); \
    float dl2 = softplus_f(d2 + bias), dl3 = softplus_f(d3 + bias); \
    float du0 = dl0 * U4.x, du1 = dl1 * U4.y; \
    float du2 = dl2 * U4.z, du3 = dl3 * U4.w; \
    const float* natp = ws + FO_NAT + d; \
    float y0 = 0.f, y1 = 0.f, y2 = 0.f, y3 = 0.f; \
    _Pragma("unroll") \
    for (int n = 0; n < NST; ++n) { \
        float an = natp[n * DE]; \
        float4 bn = *(const float4*)&WXD[(RNK + n) * 4]; \
        float4 cn = *(const float4*)&WXD[(RNK + NST + n) * 4]; \
        float h = du0 * bn.x; \
        y0 = fmaf(h, cn.x, y0); \
        h = fmaf(du1, bn.y, __expf(dl1 * an) * h); \
        y1 = fmaf(h, cn.y, y1); \
        h = fmaf(du2, bn.z, __expf(dl2 * an) * h); \
        y2 = fmaf(h, cn.z, y2); \
        h = fmaf(du3, bn.w, __expf(dl3 * an) * h); \
        y3 = fmaf(h, cn.w, y3); \
    } \
    float Dd = dvec[d]; \
    YOUT.x = fmaf(Dd, U4.x, y0); YOUT.y = fmaf(Dd, U4.y, y1); \
    YOUT.z = fmaf(Dd, U4.z, y2); YOUT.w = fmaf(Dd, U4.w, y3); }

#define LN_STATS(Y0, Y1, Y2, MU, RS) { \
    float4 s4, q4; \
    s4.x = Y0.x + Y1.x + Y2.x; s4.y = Y0.y + Y1.y + Y2.y; \
    s4.z = Y0.z + Y1.z + Y2.z; s4.w = Y0.w + Y1.w + Y2.w; \
    q4.x = Y0.x * Y0.x + Y1.x * Y1.x + Y2.x * Y2.x; \
    q4.y = Y0.y * Y0.y + Y1.y * Y1.y + Y2.y * Y2.y; \
    q4.z = Y0.z * Y0.z + Y1.z * Y1.z + Y2.z * Y2.z; \
    q4.w = Y0.w * Y0.w + Y1.w * Y1.w + Y2.w * Y2.w; \
    _Pragma("unroll") \
    for (int off = 1; off < 64; off <<= 1) { \
        s4.x += __shfl_xor(s4.x, off); s4.y += __shfl_xor(s4.y, off); \
        s4.z += __shfl_xor(s4.z, off); s4.w += __shfl_xor(s4.w, off); \
        q4.x += __shfl_xor(q4.x, off); q4.y += __shfl_xor(q4.y, off); \
        q4.z += __shfl_xor(q4.z, off); q4.w += __shfl_xor(q4.w, off); \
    } \
    const float inv = 1.f / DE; \
    MU.x = s4.x * inv; MU.y = s4.y * inv; \
    MU.z = s4.z * inv; MU.w = s4.w * inv; \
    RS.x = rsqrtf(q4.x * inv - MU.x * MU.x + 1e-5f); \
    RS.y = rsqrtf(q4.y * inv - MU.y * MU.y + 1e-5f); \
    RS.z = rsqrtf(q4.z * inv - MU.z * MU.z + 1e-5f); \
    RS.w = rsqrtf(q4.w * inv - MU.w * MU.w + 1e-5f); }

#define LN2_K(WU, K, Y4, MU, RS) { \
    const int d = lane + 64 * (K); \
    float4 Z4 = *(const float4*)&WU[4 * DE + 4 * d]; \
    float ga = gamma_[d], be = beta_[d]; \
    float4 o; \
    o.x = fmaf((Y4.x - MU.x) * RS.x, ga, be) * Z4.x; \
    o.y = fmaf((Y4.y - MU.y) * RS.y, ga, be) * Z4.y; \
    o.z = fmaf((Y4.z - MU.z) * RS.z, ga, be) * Z4.z; \
    o.w = fmaf((Y4.w - MU.w) * RS.w, ga, be) * Z4.w; \
    *(float4*)&WU[4 * d] = o; }

    {   // seq A
        float4 yA0, yA1, yA2, muA, rsA;
        SCAN_K(UA, XDA, 0, yA0)
        SCAN_K(UA, XDA, 1, yA1)
        SCAN_K(UA, XDA, 2, yA2)
        LN_STATS(yA0, yA1, yA2, muA, rsA)
        LN2_K(UA, 0, yA0, muA, rsA)
        LN2_K(UA, 1, yA1, muA, rsA)
        LN2_K(UA, 2, yA2, muA, rsA)
    }
    {   // seq B
        float4 yB0, yB1, yB2, muB, rsB;
        SCAN_K(UB, XDB, 0, yB0)
        SCAN_K(UB, XDB, 1, yB1)
        SCAN_K(UB, XDB, 2, yB2)
        LN_STATS(yB0, yB1, yB2, muB, rsB)
        LN2_K(UB, 0, yB0, muB, rsB)
        LN2_K(UB, 1, yB1, muB, rsB)
        LN2_K(UB, 2, yB2, muB, rsB)
    }
#undef SCAN_K
#undef LN_STATS
#undef LN2_K

    __syncthreads();   // all yz written; xd now dead

    // ---------- P-D: out = yz @ Wout^T via split-bf16 MFMA ----------
    // waves 0,1 -> row-tile 0 (seqs 0-3); waves 2,3 -> row-tile 1 (seqs 4-7);
    // nt base alternates 0 / 3.
    {
        const int mtD = wv >> 1;
        const int ntb = (wv & 1) * 3;
        f32x4 zz = {0.f, 0.f, 0.f, 0.f};
        f32x4 oc[3]; oc[0] = zz; oc[1] = zz; oc[2] = zz;
        const short8* woh = (const short8*)(wsu + UO_WOH);
        const short8* wol = (const short8*)(wsu + UO_WOL);
        #pragma unroll
        for (int kt = 0; kt < 6; ++kt) {
            short8 ah, al;
            BUILD_A(ah, al, mtD, kt, UZ_OFF, UZSTR)   // yz lives in u region
            #pragma unroll
            for (int t = 0; t < 3; ++t) {
                int fi = (kt * 6 + ntb + t) * 64 + lane;
                short8 bh = woh[fi], bl = wol[fi];
                oc[t] = MFMA(ah, bh, oc[t]);
                oc[t] = MFMA(al, bh, oc[t]);
                oc[t] = MFMA(ah, bl, oc[t]);
            }
        }
        // scatter to A-region as [s][dd*4+l] (contiguous, stride 384)
        const int g = lane >> 4, c = lane & 15;
        #pragma unroll
        for (int t = 0; t < 3; ++t) {
            int dd = 16 * (ntb + t) + c;
            #pragma unroll
            for (int r = 0; r < 4; ++r) {
                int row = mtD * 16 + g * 4 + r;
                lds[AS_OFF + (row >> 2) * NJ + 4 * dd + (row & 3)] = oc[t][r];
            }
        }
    }
    __syncthreads();

    // ---------- coalesced float4 store ----------
    {
        float4* og = (float4*)(out + (size_t)blk * SEQ_PB * NJ);
        for (int i = tid; i < SEQ_PB * NJ / 4; i += THREADS)
            og[i] = *(const float4*)&lds[AS_OFF + 4 * i];
    }
}

extern "C" void kernel_launch(void* const* d_in, const int* in_sizes, int n_in,
                              void* d_out, int out_size, void* d_ws, size_t ws_size,
                              hipStream_t stream) {
    (void)n_in; (void)ws_size; (void)out_size;
    int nseq = in_sizes[0] / NJ;            // 12544 = 4*56*56
    int grid = nseq / SEQ_PB;               // 1568 blocks
    if (grid < 1) grid = 1;
    float* ws = (float*)d_ws;               // 238 KB used (same as v9)

    prep_weights<<<64, THREADS, 0, stream>>>(
        (const float*)d_in[1],  // in_proj_w
        (const float*)d_in[9],  // out_proj_w
        (const float*)d_in[5],  // A_logs
        (const float*)d_in[3],  // dt_projs_weight
        ws);

    ssm_fused10<<<grid, THREADS, 0, stream>>>(
        (const float*)d_in[0],  // x
        (const float*)d_in[2],  // x_proj_weight
        (const float*)d_in[4],  // dt_projs_bias
        (const float*)d_in[6],  // Ds
        (const float*)d_in[7],  // ln_gamma
        (const float*)d_in[8],  // ln_beta
        ws,
        (float*)d_out);
}